// Round 4
// baseline (51.006 us; speedup 1.0000x reference)
//
#include <hip/hip_runtime.h>

// Output = encode_output.sum(axis=1): [B, S, EOUT] -> [B, 1, EOUT]
// (softmax over a size-1 axis == 1.0, so the MLP branch is dead code)
//
// R1 winner structure (46.9 us): 1024 blocks x 256 thr, block (b,ec) owns a
// 32-float chunk, 32-way s-split, thread reads float4 at 4 KiB row stride.
// Deltas this round: nontemporal loads (zero-reuse stream, skip L2 pollution)
// + 8 independent accumulator chains (8 loads each) for deeper MLP queue.

constexpr int B_   = 32;
constexpr int S_   = 2048;
constexpr int EOUT = 1024;        // 2 * ENC_H
constexpr int RS   = EOUT / 4;    // row stride in float4 = 256
constexpr int ECH  = 32;          // e-chunks per batch (32 floats each)
constexpr int TPB  = 256;
constexpr int SSPL = TPB / 8;     // 32-way s-split

typedef float f4v __attribute__((ext_vector_type(4)));

__global__ __launch_bounds__(TPB) void rowsum_kernel(const float* __restrict__ enc,
                                                     float* __restrict__ out) {
    const int bx  = blockIdx.x;
    const int b   = bx >> 5;          // / ECH
    const int ec  = bx & (ECH - 1);
    const int tid = threadIdx.x;
    const int e4  = tid & 7;          // float4 within the 32-float chunk
    const int ss  = tid >> 3;         // 0..31 s-split lane

    const f4v* base = reinterpret_cast<const f4v*>(enc + (size_t)b * S_ * EOUT + ec * 32) + e4;

    f4v a0 = {0.f,0.f,0.f,0.f}, a1 = {0.f,0.f,0.f,0.f};
    f4v a2 = {0.f,0.f,0.f,0.f}, a3 = {0.f,0.f,0.f,0.f};
    f4v a4 = {0.f,0.f,0.f,0.f}, a5 = {0.f,0.f,0.f,0.f};
    f4v a6 = {0.f,0.f,0.f,0.f}, a7 = {0.f,0.f,0.f,0.f};

    // rows s = ss + k*32; 64 loads/thread, 8 independent chains
    #pragma unroll
    for (int s = 0; s < S_; s += 8 * SSPL) {
        a0 += __builtin_nontemporal_load(base + (size_t)(s + ss           ) * RS);
        a1 += __builtin_nontemporal_load(base + (size_t)(s + ss +     SSPL) * RS);
        a2 += __builtin_nontemporal_load(base + (size_t)(s + ss + 2 * SSPL) * RS);
        a3 += __builtin_nontemporal_load(base + (size_t)(s + ss + 3 * SSPL) * RS);
        a4 += __builtin_nontemporal_load(base + (size_t)(s + ss + 4 * SSPL) * RS);
        a5 += __builtin_nontemporal_load(base + (size_t)(s + ss + 5 * SSPL) * RS);
        a6 += __builtin_nontemporal_load(base + (size_t)(s + ss + 6 * SSPL) * RS);
        a7 += __builtin_nontemporal_load(base + (size_t)(s + ss + 7 * SSPL) * RS);
    }
    f4v acc = ((a0 + a1) + (a2 + a3)) + ((a4 + a5) + (a6 + a7));

    __shared__ f4v lds[TPB];
    lds[tid] = acc;
    __syncthreads();

    #pragma unroll
    for (int off = TPB / 2; off >= 8; off >>= 1) {
        if (tid < off) {
            f4v t = lds[tid + off];
            lds[tid] += t;
        }
        __syncthreads();
    }

    if (tid < 8) {
        f4v r = lds[tid];
        reinterpret_cast<f4v*>(out + (size_t)b * EOUT + ec * 32)[tid] = r;
    }
}

extern "C" void kernel_launch(void* const* d_in, const int* in_sizes, int n_in,
                              void* d_out, int out_size, void* d_ws, size_t ws_size,
                              hipStream_t stream) {
    const float* enc = (const float*)d_in[0];
    float* out = (float*)d_out;
    rowsum_kernel<<<dim3(B_ * ECH), dim3(TPB), 0, stream>>>(enc, out);
}

// Round 5
// 46.958 us; speedup vs baseline: 1.0862x; 1.0862x over previous
//
#include <hip/hip_runtime.h>

// Output = encode_output.sum(axis=1): [B, S, EOUT] -> [B, 1, EOUT]
// (softmax over a size-1 axis == 1.0, so the MLP branch is dead code)
//
// R1 winner (46.9 us, 5.72 TB/s effective ~ 91% of measured read ceiling;
// ~98% after ~3-4 us graph-replay overhead). Tested and REJECTED:
//   R2 contiguous 2-kernel (+nt): 48.0 us
//   R3 512-thr / 32 waves/CU (+nt): 49.7 us
//   R4 nontemporal + 8 chains:      51.0 us
// Conclusion: plain cached float4 loads, 1024 blocks x 256 thr (16 waves/CU),
// 4 independent accumulator chains is the read-stream roofline configuration.

constexpr int B_    = 32;
constexpr int S_    = 2048;
constexpr int EOUT  = 1024;           // 2 * ENC_H
constexpr int E4PB  = 8;              // float4 per block chunk (32 floats)
constexpr int ECH   = EOUT / (E4PB * 4); // 32 e-chunks per batch
constexpr int SSPL  = 32;             // s-split ways per block

__device__ __forceinline__ void f4acc(float4& a, const float4 b) {
    a.x += b.x; a.y += b.y; a.z += b.z; a.w += b.w;
}

__global__ __launch_bounds__(256) void rowsum_kernel(const float* __restrict__ enc,
                                                     float* __restrict__ out) {
    const int bx  = blockIdx.x;
    const int b   = bx >> 5;          // / ECH
    const int ec  = bx & (ECH - 1);
    const int tid = threadIdx.x;
    const int e4  = tid & (E4PB - 1); // which float4 within chunk
    const int ss  = tid >> 3;         // 0..31  s-split lane

    const float4* base =
        reinterpret_cast<const float4*>(enc + (size_t)b * S_ * EOUT + ec * (E4PB * 4)) + e4;
    constexpr int RS = EOUT / 4;      // row stride in float4 = 256

    float4 a0 = make_float4(0.f, 0.f, 0.f, 0.f);
    float4 a1 = make_float4(0.f, 0.f, 0.f, 0.f);
    float4 a2 = make_float4(0.f, 0.f, 0.f, 0.f);
    float4 a3 = make_float4(0.f, 0.f, 0.f, 0.f);

    // s = ss, ss+32, ... : 64 loads/thread, 4 independent accumulators
    #pragma unroll
    for (int s = 0; s < S_; s += 4 * SSPL) {
        f4acc(a0, base[(size_t)(s + ss) * RS]);
        f4acc(a1, base[(size_t)(s + ss + SSPL) * RS]);
        f4acc(a2, base[(size_t)(s + ss + 2 * SSPL) * RS]);
        f4acc(a3, base[(size_t)(s + ss + 3 * SSPL) * RS]);
    }
    f4acc(a0, a1); f4acc(a2, a3); f4acc(a0, a2);

    __shared__ float4 lds[256];
    lds[tid] = a0;
    __syncthreads();

    #pragma unroll
    for (int off = 128; off >= E4PB; off >>= 1) {
        if (tid < off) {
            float4 t = lds[tid + off];
            f4acc(lds[tid], t);
        }
        __syncthreads();
    }

    if (tid < E4PB) {
        float4 r = lds[tid];
        reinterpret_cast<float4*>(out + (size_t)b * EOUT + ec * (E4PB * 4))[tid] = r;
    }
}

extern "C" void kernel_launch(void* const* d_in, const int* in_sizes, int n_in,
                              void* d_out, int out_size, void* d_ws, size_t ws_size,
                              hipStream_t stream) {
    const float* enc = (const float*)d_in[0];
    float* out = (float*)d_out;
    rowsum_kernel<<<dim3(B_ * ECH), dim3(256), 0, stream>>>(enc, out);
}